// Round 4
// baseline (275.928 us; speedup 1.0000x reference)
//
#include <hip/hip_runtime.h>

typedef unsigned int u32;
typedef unsigned long long u64;

#define NB 32
#define NCLS 80
#define NANCHOR 8400
#define PRE 1000
#define MAXDET 100
#define MROWS 1024   // mask rows (padded)

// ws layout (floats):
//   [0 .. 268800)               scores[b][a] (decode out; reused per image for sorted data)
//   [268800 .. 5*268800)        boxes float4[b][a]
//   [5*268800 .. 6*268800)      cls int[b][a]
//   [6*268800 .. +1M u64]       suppression mask u64[32][16][1024]  (4 MB)
// Per-image sorted region (reuses scores area, float offset b*8400):
//   sbox float4[1024] (4096 f) | skey u64[1024] (2048 f) | sarea float[1024] (1024 f)

// ---------------------------------------------------------------------------
// Kernel 1: decode. One thread per (image, anchor). (proven)
// ---------------------------------------------------------------------------
__global__ void decode_kernel(const float* __restrict__ cls0, const float* __restrict__ box0,
                              const float* __restrict__ cls1, const float* __restrict__ box1,
                              const float* __restrict__ cls2, const float* __restrict__ box2,
                              float* __restrict__ ws_scores, float4* __restrict__ ws_boxes,
                              int* __restrict__ ws_cls) {
    int g = blockIdx.x * blockDim.x + threadIdx.x;
    if (g >= NB * NANCHOR) return;
    int b = g / NANCHOR;
    int r = g - b * NANCHOR;

    const float* cp; const float* bp;
    int HW, hw, h, w, step;
    if (r < 6400) {
        cp = cls0 + (size_t)b * NCLS * 6400; bp = box0 + (size_t)b * 4 * 6400;
        HW = 6400; hw = r;        h = hw / 80; w = hw - h * 80; step = 8;
    } else if (r < 8000) {
        cp = cls1 + (size_t)b * NCLS * 1600; bp = box1 + (size_t)b * 4 * 1600;
        HW = 1600; hw = r - 6400; h = hw / 40; w = hw - h * 40; step = 16;
    } else {
        cp = cls2 + (size_t)b * NCLS * 400;  bp = box2 + (size_t)b * 4 * 400;
        HW = 400;  hw = r - 8000; h = hw / 20; w = hw - h * 20; step = 32;
    }

    float m = cp[hw];
    int ci = 0;
    for (int c = 1; c < NCLS; ++c) {
        float v = cp[(size_t)c * HW + hw];
        if (v > m) { m = v; ci = c; }
    }
    float score = 1.0f / (1.0f + expf(-m));

    float l = bp[hw], t = bp[HW + hw], rr = bp[2 * HW + hw], bo = bp[3 * HW + hw];
    float gx = (float)(w * step), gy = (float)(h * step);

    ws_scores[g] = score;
    ws_boxes[g] = make_float4(gx - l, gy - t, gx + rr, gy + bo);
    ws_cls[g] = ci;
}

// wave-level inclusive suffix scan (sum over lanes >= my lane)
__device__ __forceinline__ int wave_suffix_incl(int v, int lane) {
    #pragma unroll
    for (int off = 1; off < 64; off <<= 1) {
        int t = __shfl_down(v, off);
        if (lane + off < 64) v += t;
    }
    return v;
}

// ---------------------------------------------------------------------------
// Kernel 2: per-image radix-select + compact + O(n^2) rank sort. (proven)
// ---------------------------------------------------------------------------
__global__ __launch_bounds__(1024) void select_kernel(float* ws,
                                                      const float4* __restrict__ ws_boxes,
                                                      const int* __restrict__ ws_cls) {
    const int b = blockIdx.x;
    const int tid = threadIdx.x;
    const int lane = tid & 63;
    const int wv = tid >> 6;

    __shared__ int s_hist[4][1024];
    __shared__ u64 s_key[2048];
    __shared__ int s_wtot[16];
    __shared__ int s_C, s_base, s_cnt;
    __shared__ u32 s_thresh;

    const float* sc = ws + (size_t)b * NANCHOR;
    float4* sbox = (float4*)(ws + (size_t)b * NANCHOR);
    u64*    skey = (u64*)(ws + (size_t)b * NANCHOR + 4096);
    float*  sarea = ws + (size_t)b * NANCHOR + 6144;

    u32 sb[9];
    #pragma unroll
    for (int k = 0; k < 9; ++k) {
        int a = tid + (k << 10);
        sb[k] = (a < NANCHOR) ? __float_as_uint(sc[a]) : 0u;
    }
    int* hp = &s_hist[0][0];
    hp[tid] = 0; hp[tid + 1024] = 0; hp[tid + 2048] = 0; hp[tid + 3072] = 0;
    if (tid == 0) s_cnt = 0;
    __syncthreads();

    #pragma unroll
    for (int k = 0; k < 9; ++k) {
        int a = tid + (k << 10);
        if (a < NANCHOR) atomicAdd(&s_hist[wv & 3][sb[k] >> 20], 1);
    }
    __syncthreads();
    {
        int v = s_hist[0][tid] + s_hist[1][tid] + s_hist[2][tid] + s_hist[3][tid];
        int wincl = wave_suffix_incl(v, lane);
        if (lane == 0) s_wtot[wv] = wincl;
        __syncthreads();
        int add = 0;
        #pragma unroll
        for (int w = 0; w < 16; ++w) if (w > wv) add += s_wtot[w];
        int sfx = wincl + add;
        int nxt = sfx - v;
        if (sfx >= PRE && nxt < PRE) { s_C = tid; s_base = nxt; }
        hp[tid] = 0; hp[tid + 1024] = 0; hp[tid + 2048] = 0; hp[tid + 3072] = 0;
    }
    __syncthreads();
    const int C = s_C, base0 = s_base;

    #pragma unroll
    for (int k = 0; k < 9; ++k) {
        int a = tid + (k << 10);
        if (a < NANCHOR && (int)(sb[k] >> 20) == C)
            atomicAdd(&s_hist[wv & 3][(sb[k] >> 10) & 1023], 1);
    }
    __syncthreads();
    {
        int v = s_hist[0][tid] + s_hist[1][tid] + s_hist[2][tid] + s_hist[3][tid];
        int wincl = wave_suffix_incl(v, lane);
        if (lane == 0) s_wtot[wv] = wincl;
        __syncthreads();
        int add = 0;
        #pragma unroll
        for (int w = 0; w < 16; ++w) if (w > wv) add += s_wtot[w];
        int sfx = wincl + add;
        int nxt = sfx - v;
        if (base0 + sfx >= PRE && base0 + nxt < PRE)
            s_thresh = ((u32)C << 20) | ((u32)tid << 10);
    }
    __syncthreads();
    const u32 T = s_thresh;

    #pragma unroll
    for (int k = 0; k < 9; ++k) {
        int a = tid + (k << 10);
        bool pred = (a < NANCHOR) && (sb[k] >= T);
        u64 mask = __ballot(pred);
        if (pred) {
            int leader = __ffsll((long long)mask) - 1;
            int bpos = 0;
            if (lane == leader) bpos = atomicAdd(&s_cnt, __popcll(mask));
            bpos = __shfl(bpos, leader);
            int pos = bpos + __popcll(mask & ((1ULL << lane) - 1ULL));
            if (pos < 2048)
                s_key[pos] = ((u64)sb[k] << 14) | (u64)(NANCHOR - 1 - a);
        }
    }
    __syncthreads();

    int cnt = s_cnt; if (cnt > 2048) cnt = 2048;
    for (int slot = tid; slot < cnt; slot += 1024) {
        u64 me = s_key[slot];
        int rank = 0;
        int y = 0;
        for (; y + 4 <= cnt; y += 4) {
            rank += (int)(s_key[y] > me) + (int)(s_key[y + 1] > me)
                  + (int)(s_key[y + 2] > me) + (int)(s_key[y + 3] > me);
        }
        for (; y < cnt; ++y) rank += (int)(s_key[y] > me);
        if (rank < PRE) {
            int idx = (NANCHOR - 1) - (int)(me & 16383ULL);
            float4 bx = ws_boxes[(size_t)b * NANCHOR + idx];
            int c = ws_cls[(size_t)b * NANCHOR + idx];
            float off = (float)c * 4096.0f;
            float x1 = bx.x + off, y1 = bx.y + off, x2 = bx.z + off, y2 = bx.w + off;
            sbox[rank] = make_float4(x1, y1, x2, y2);
            sarea[rank] = fmaxf(x2 - x1, 0.0f) * fmaxf(y2 - y1, 0.0f);
            skey[rank] = me;
        }
    }
}

// ---------------------------------------------------------------------------
// Kernel 3: suppression bit-matrix. blockIdx = b*64 + w*4 + rowblock.
// Thread = one (row, jword): 64 IoUs -> one u64. All parallel, full chip.
// ---------------------------------------------------------------------------
__global__ __launch_bounds__(256) void iou_mask_kernel(const float* __restrict__ ws,
                                                       u64* __restrict__ mask) {
    const int bid = blockIdx.x;
    const int b = bid >> 6;
    const int w = (bid >> 2) & 15;
    const int rblk = bid & 3;
    const int tid = threadIdx.x;

    const float4* sbox = (const float4*)(ws + (size_t)b * NANCHOR);
    const float*  sarea = ws + (size_t)b * NANCHOR + 6144;

    __shared__ float4 s_jb[64];
    __shared__ float s_ja[64];
    if (tid < 64) {
        int j = w * 64 + tid;
        if (j < PRE) { s_jb[tid] = sbox[j]; s_ja[tid] = sarea[j]; }
        else { s_jb[tid] = make_float4(-4e8f, -4e8f, -4e8f, -4e8f); s_ja[tid] = 0.f; }
    }
    __syncthreads();

    const int row = rblk * 256 + tid;
    if (row >= MROWS) return;
    u64* mp = mask + ((size_t)b * 16 + w) * MROWS + row;
    if (row >= PRE) { *mp = 0ULL; return; }

    float4 bi = sbox[row];
    float ai = sarea[row];
    u64 bits = 0;
    #pragma unroll
    for (int k = 0; k < 64; ++k) {
        int j = w * 64 + k;
        float lx = fmaxf(bi.x, s_jb[k].x);
        float ly = fmaxf(bi.y, s_jb[k].y);
        float rx = fminf(bi.z, s_jb[k].z);
        float ry = fminf(bi.w, s_jb[k].w);
        float wx = fmaxf(rx - lx, 0.0f);
        float wy = fmaxf(ry - ly, 0.0f);
        float inter = wx * wy;
        float den = ai + s_ja[k] - inter + 1e-7f;   // ((ai+aj)-inter)+eps
        bool s = (j > row) && (j < PRE) && (inter > 0.5f * den);
        bits |= s ? (1ULL << k) : 0ULL;
    }
    *mp = bits;
}

// ---------------------------------------------------------------------------
// Kernel 4: serial greedy scan over the bitmap. One wave/image; all lanes
// redundantly hold removed[16] in registers. Skips are free (ctz advance).
// ---------------------------------------------------------------------------
__global__ __launch_bounds__(64) void nms_scan_kernel(const float* __restrict__ ws,
                                                      const u64* __restrict__ mask,
                                                      const float4* __restrict__ ws_boxes,
                                                      const int* __restrict__ ws_cls,
                                                      float* __restrict__ out) {
    const int b = blockIdx.x;
    const int lane = threadIdx.x;
    const u64* m = mask + (size_t)b * 16 * MROWS;
    const u64* skey = (const u64*)(ws + (size_t)b * NANCHOR + 4096);

    __shared__ int s_keep[MAXDET];

    u64 removed[16];
    #pragma unroll
    for (int w = 0; w < 16; ++w) removed[w] = 0ULL;

    int nk = 0;
    int i = 0;
    while (true) {
        if (lane == 0) s_keep[nk] = i;
        nk++;
        if (nk >= MAXDET) break;
        #pragma unroll
        for (int w = 0; w < 16; ++w) removed[w] |= m[(size_t)w * MROWS + i];
        // advance to next clear bit > i
        int ip = i + 1;
        int w0 = ip >> 6, b0 = ip & 63;
        int ni = -1;
        #pragma unroll
        for (int w = 0; w < 16; ++w) {
            u64 avail = ~removed[w];
            if (w < w0) avail = 0ULL;
            else if (w == w0) avail &= (~0ULL) << b0;
            if (ni < 0 && avail) ni = w * 64 + (int)__builtin_ctzll(avail);
        }
        if (ni < 0 || ni >= PRE) break;
        i = ni;
    }
    __syncthreads();

    // outputs: boxes_with_scores [32][100][5], then classes [32][100]
    #pragma unroll
    for (int t = 0; t < 2; ++t) {
        int r = lane + (t << 6);
        if (r < MAXDET) {
            float* o = out + ((size_t)b * MAXDET + r) * 5;
            float* oc = out + (size_t)NB * MAXDET * 5 + (size_t)b * MAXDET + r;
            if (r < nk) {
                int i2 = s_keep[r];
                u64 key = skey[i2];
                int idx = (NANCHOR - 1) - (int)(key & 16383ULL);
                float score = __uint_as_float((u32)(key >> 14));
                float4 bx = ws_boxes[(size_t)b * NANCHOR + idx];
                int c = ws_cls[(size_t)b * NANCHOR + idx];
                o[0] = bx.x; o[1] = bx.y; o[2] = bx.z; o[3] = bx.w; o[4] = score;
                *oc = (float)c;
            } else {
                o[0] = 0.0f; o[1] = 0.0f; o[2] = 0.0f; o[3] = 0.0f; o[4] = 0.0f;
                *oc = -1.0f;
            }
        }
    }
}

extern "C" void kernel_launch(void* const* d_in, const int* in_sizes, int n_in,
                              void* d_out, int out_size, void* d_ws, size_t ws_size,
                              hipStream_t stream) {
    const float* cls0 = (const float*)d_in[0];
    const float* box0 = (const float*)d_in[1];
    const float* cls1 = (const float*)d_in[2];
    const float* box1 = (const float*)d_in[3];
    const float* cls2 = (const float*)d_in[4];
    const float* box2 = (const float*)d_in[5];

    float* ws = (float*)d_ws;
    float* ws_scores = ws;                                   // 268800 floats (reused for sorted data)
    float4* ws_boxes = (float4*)(ws + NB * NANCHOR);         // 268800 float4
    int* ws_cls = (int*)(ws + (size_t)NB * NANCHOR * 5);     // 268800 ints
    u64* ws_mask = (u64*)(ws + (size_t)NB * NANCHOR * 6);    // u64[32][16][1024] = 4 MB

    int total = NB * NANCHOR;
    decode_kernel<<<(total + 255) / 256, 256, 0, stream>>>(
        cls0, box0, cls1, box1, cls2, box2, ws_scores, ws_boxes, ws_cls);

    select_kernel<<<NB, 1024, 0, stream>>>(ws, ws_boxes, ws_cls);

    iou_mask_kernel<<<NB * 64, 256, 0, stream>>>(ws, ws_mask);

    nms_scan_kernel<<<NB, 64, 0, stream>>>(ws, ws_mask, ws_boxes, ws_cls, (float*)d_out);
}

// Round 5
// 223.780 us; speedup vs baseline: 1.2330x; 1.2330x over previous
//
#include <hip/hip_runtime.h>

typedef unsigned int u32;
typedef unsigned long long u64;

#define NB 32
#define NCLS 80
#define NANCHOR 8400
#define PRE 1000
#define MAXDET 100
#define MROWS 1024   // mask rows (padded)

// ws layout (floats):
//   [0 .. 268800)               scores[b][a] (decode out; reused per image for sorted data)
//   [268800 .. 5*268800)        boxes float4[b][a]
//   [5*268800 .. 6*268800)      cls int[b][a]
//   [6*268800 ..]               suppression mask u64[32][1024][16]  (4 MB, ROW-MAJOR)
// Per-image sorted region (reuses scores area, float offset b*8400):
//   sbox float4[1024] (4096 f) | skey u64[1024] (2048 f) | sarea float[1024] (1024 f)

// ---------------------------------------------------------------------------
// Kernel 1: decode. One thread per (image, anchor). (proven)
// ---------------------------------------------------------------------------
__global__ void decode_kernel(const float* __restrict__ cls0, const float* __restrict__ box0,
                              const float* __restrict__ cls1, const float* __restrict__ box1,
                              const float* __restrict__ cls2, const float* __restrict__ box2,
                              float* __restrict__ ws_scores, float4* __restrict__ ws_boxes,
                              int* __restrict__ ws_cls) {
    int g = blockIdx.x * blockDim.x + threadIdx.x;
    if (g >= NB * NANCHOR) return;
    int b = g / NANCHOR;
    int r = g - b * NANCHOR;

    const float* cp; const float* bp;
    int HW, hw, h, w, step;
    if (r < 6400) {
        cp = cls0 + (size_t)b * NCLS * 6400; bp = box0 + (size_t)b * 4 * 6400;
        HW = 6400; hw = r;        h = hw / 80; w = hw - h * 80; step = 8;
    } else if (r < 8000) {
        cp = cls1 + (size_t)b * NCLS * 1600; bp = box1 + (size_t)b * 4 * 1600;
        HW = 1600; hw = r - 6400; h = hw / 40; w = hw - h * 40; step = 16;
    } else {
        cp = cls2 + (size_t)b * NCLS * 400;  bp = box2 + (size_t)b * 4 * 400;
        HW = 400;  hw = r - 8000; h = hw / 20; w = hw - h * 20; step = 32;
    }

    float m = cp[hw];
    int ci = 0;
    for (int c = 1; c < NCLS; ++c) {
        float v = cp[(size_t)c * HW + hw];
        if (v > m) { m = v; ci = c; }
    }
    float score = 1.0f / (1.0f + expf(-m));

    float l = bp[hw], t = bp[HW + hw], rr = bp[2 * HW + hw], bo = bp[3 * HW + hw];
    float gx = (float)(w * step), gy = (float)(h * step);

    ws_scores[g] = score;
    ws_boxes[g] = make_float4(gx - l, gy - t, gx + rr, gy + bo);
    ws_cls[g] = ci;
}

// wave-level inclusive suffix scan (sum over lanes >= my lane)
__device__ __forceinline__ int wave_suffix_incl(int v, int lane) {
    #pragma unroll
    for (int off = 1; off < 64; off <<= 1) {
        int t = __shfl_down(v, off);
        if (lane + off < 64) v += t;
    }
    return v;
}

// ---------------------------------------------------------------------------
// Kernel 2: per-image radix-select + compact + O(n^2) rank sort. (proven)
// ---------------------------------------------------------------------------
__global__ __launch_bounds__(1024) void select_kernel(float* ws,
                                                      const float4* __restrict__ ws_boxes,
                                                      const int* __restrict__ ws_cls) {
    const int b = blockIdx.x;
    const int tid = threadIdx.x;
    const int lane = tid & 63;
    const int wv = tid >> 6;

    __shared__ int s_hist[4][1024];
    __shared__ u64 s_key[2048];
    __shared__ int s_wtot[16];
    __shared__ int s_C, s_base, s_cnt;
    __shared__ u32 s_thresh;

    const float* sc = ws + (size_t)b * NANCHOR;
    float4* sbox = (float4*)(ws + (size_t)b * NANCHOR);
    u64*    skey = (u64*)(ws + (size_t)b * NANCHOR + 4096);
    float*  sarea = ws + (size_t)b * NANCHOR + 6144;

    u32 sb[9];
    #pragma unroll
    for (int k = 0; k < 9; ++k) {
        int a = tid + (k << 10);
        sb[k] = (a < NANCHOR) ? __float_as_uint(sc[a]) : 0u;
    }
    int* hp = &s_hist[0][0];
    hp[tid] = 0; hp[tid + 1024] = 0; hp[tid + 2048] = 0; hp[tid + 3072] = 0;
    if (tid == 0) s_cnt = 0;
    __syncthreads();

    #pragma unroll
    for (int k = 0; k < 9; ++k) {
        int a = tid + (k << 10);
        if (a < NANCHOR) atomicAdd(&s_hist[wv & 3][sb[k] >> 20], 1);
    }
    __syncthreads();
    {
        int v = s_hist[0][tid] + s_hist[1][tid] + s_hist[2][tid] + s_hist[3][tid];
        int wincl = wave_suffix_incl(v, lane);
        if (lane == 0) s_wtot[wv] = wincl;
        __syncthreads();
        int add = 0;
        #pragma unroll
        for (int w = 0; w < 16; ++w) if (w > wv) add += s_wtot[w];
        int sfx = wincl + add;
        int nxt = sfx - v;
        if (sfx >= PRE && nxt < PRE) { s_C = tid; s_base = nxt; }
        hp[tid] = 0; hp[tid + 1024] = 0; hp[tid + 2048] = 0; hp[tid + 3072] = 0;
    }
    __syncthreads();
    const int C = s_C, base0 = s_base;

    #pragma unroll
    for (int k = 0; k < 9; ++k) {
        int a = tid + (k << 10);
        if (a < NANCHOR && (int)(sb[k] >> 20) == C)
            atomicAdd(&s_hist[wv & 3][(sb[k] >> 10) & 1023], 1);
    }
    __syncthreads();
    {
        int v = s_hist[0][tid] + s_hist[1][tid] + s_hist[2][tid] + s_hist[3][tid];
        int wincl = wave_suffix_incl(v, lane);
        if (lane == 0) s_wtot[wv] = wincl;
        __syncthreads();
        int add = 0;
        #pragma unroll
        for (int w = 0; w < 16; ++w) if (w > wv) add += s_wtot[w];
        int sfx = wincl + add;
        int nxt = sfx - v;
        if (base0 + sfx >= PRE && base0 + nxt < PRE)
            s_thresh = ((u32)C << 20) | ((u32)tid << 10);
    }
    __syncthreads();
    const u32 T = s_thresh;

    #pragma unroll
    for (int k = 0; k < 9; ++k) {
        int a = tid + (k << 10);
        bool pred = (a < NANCHOR) && (sb[k] >= T);
        u64 mask = __ballot(pred);
        if (pred) {
            int leader = __ffsll((long long)mask) - 1;
            int bpos = 0;
            if (lane == leader) bpos = atomicAdd(&s_cnt, __popcll(mask));
            bpos = __shfl(bpos, leader);
            int pos = bpos + __popcll(mask & ((1ULL << lane) - 1ULL));
            if (pos < 2048)
                s_key[pos] = ((u64)sb[k] << 14) | (u64)(NANCHOR - 1 - a);
        }
    }
    __syncthreads();

    int cnt = s_cnt; if (cnt > 2048) cnt = 2048;
    for (int slot = tid; slot < cnt; slot += 1024) {
        u64 me = s_key[slot];
        int rank = 0;
        int y = 0;
        for (; y + 4 <= cnt; y += 4) {
            rank += (int)(s_key[y] > me) + (int)(s_key[y + 1] > me)
                  + (int)(s_key[y + 2] > me) + (int)(s_key[y + 3] > me);
        }
        for (; y < cnt; ++y) rank += (int)(s_key[y] > me);
        if (rank < PRE) {
            int idx = (NANCHOR - 1) - (int)(me & 16383ULL);
            float4 bx = ws_boxes[(size_t)b * NANCHOR + idx];
            int c = ws_cls[(size_t)b * NANCHOR + idx];
            float off = (float)c * 4096.0f;
            float x1 = bx.x + off, y1 = bx.y + off, x2 = bx.z + off, y2 = bx.w + off;
            sbox[rank] = make_float4(x1, y1, x2, y2);
            sarea[rank] = fmaxf(x2 - x1, 0.0f) * fmaxf(y2 - y1, 0.0f);
            skey[rank] = me;
        }
    }
}

// ---------------------------------------------------------------------------
// Kernel 3: suppression bit-matrix, ROW-MAJOR mask[b][row][16].
// blockIdx = b*64 + w*4 + rowblock; thread = one (row, jword).
// ---------------------------------------------------------------------------
__global__ __launch_bounds__(256) void iou_mask_kernel(const float* __restrict__ ws,
                                                       u64* __restrict__ mask) {
    const int bid = blockIdx.x;
    const int b = bid >> 6;
    const int w = (bid >> 2) & 15;
    const int rblk = bid & 3;
    const int tid = threadIdx.x;

    const float4* sbox = (const float4*)(ws + (size_t)b * NANCHOR);
    const float*  sarea = ws + (size_t)b * NANCHOR + 6144;

    __shared__ float4 s_jb[64];
    __shared__ float s_ja[64];
    if (tid < 64) {
        int j = w * 64 + tid;
        if (j < PRE) { s_jb[tid] = sbox[j]; s_ja[tid] = sarea[j]; }
        else { s_jb[tid] = make_float4(-4e8f, -4e8f, -4e8f, -4e8f); s_ja[tid] = 0.f; }
    }
    __syncthreads();

    const int row = rblk * 256 + tid;
    if (row >= MROWS) return;
    u64* mp = mask + ((size_t)b * MROWS + row) * 16 + w;   // row-major
    if (row >= PRE) { *mp = 0ULL; return; }

    float4 bi = sbox[row];
    float ai = sarea[row];
    u64 bits = 0;
    #pragma unroll
    for (int k = 0; k < 64; ++k) {
        int j = w * 64 + k;
        float lx = fmaxf(bi.x, s_jb[k].x);
        float ly = fmaxf(bi.y, s_jb[k].y);
        float rx = fminf(bi.z, s_jb[k].z);
        float ry = fminf(bi.w, s_jb[k].w);
        float wx = fmaxf(rx - lx, 0.0f);
        float wy = fmaxf(ry - ly, 0.0f);
        float inter = wx * wy;
        float den = ai + s_ja[k] - inter + 1e-7f;   // ((ai+aj)-inter)+eps
        bool s = (j > row) && (j < PRE) && (inter > 0.5f * den);
        bits |= s ? (1ULL << k) : 0ULL;
    }
    *mp = bits;
}

// ---------------------------------------------------------------------------
// Kernel 4: chunked shfl-based greedy scan. One wave/image. Lane l holds
// the 16 mask words of row c*64+l in VGPRs (prefetched a chunk ahead);
// the serial walk is register+shfl only — zero memory in the inner loop.
// ---------------------------------------------------------------------------
__global__ __launch_bounds__(64) void nms_scan_kernel(const float* __restrict__ ws,
                                                      const u64* __restrict__ mask,
                                                      const float4* __restrict__ ws_boxes,
                                                      const int* __restrict__ ws_cls,
                                                      float* __restrict__ out) {
    const int b = blockIdx.x;
    const int lane = threadIdx.x;
    const u64* mbase = mask + (size_t)b * MROWS * 16;
    const u64* skey = (const u64*)(ws + (size_t)b * NANCHOR + 4096);

    __shared__ int s_keep[MAXDET];

    u64 removed[16];
    #pragma unroll
    for (int w = 0; w < 16; ++w) removed[w] = 0ULL;
    removed[15] |= (~0ULL) << 40;        // rows 1000..1023 are not candidates

    // prefetch chunk 0: lane l <- row l's 16 words (128 B contiguous)
    u64 jm[16], jn[16];
    {
        const ulonglong2* p = (const ulonglong2*)(mbase + (size_t)lane * 16);
        #pragma unroll
        for (int k = 0; k < 8; ++k) { ulonglong2 v = p[k]; jm[2 * k] = v.x; jm[2 * k + 1] = v.y; }
    }

    int nk = 0;
    for (int c = 0; c < 16 && nk < MAXDET; ++c) {
        if (c < 15) {   // prefetch next chunk
            const ulonglong2* p = (const ulonglong2*)(mbase + (size_t)((c + 1) * 64 + lane) * 16);
            #pragma unroll
            for (int k = 0; k < 8; ++k) { ulonglong2 v = p[k]; jn[2 * k] = v.x; jn[2 * k + 1] = v.y; }
        }
        u64 rc = removed[c];
        for (int l = 0; l < 64; ++l) {
            if ((rc >> l) & 1) continue;
            int r = c * 64 + l;
            if (lane == 0) s_keep[nk] = r;
            nk++;
            // OR row r's mask words (held by lane l) into removed
            #pragma unroll
            for (int w = 0; w < 16; ++w) {
                u32 lo = (u32)__shfl((int)(u32)(jm[w] & 0xffffffffULL), l);
                u32 hi = (u32)__shfl((int)(u32)(jm[w] >> 32), l);
                removed[w] |= ((u64)hi << 32) | lo;
            }
            rc = removed[c];
            if (nk >= MAXDET) break;
        }
        #pragma unroll
        for (int k = 0; k < 16; ++k) jm[k] = jn[k];
    }
    __syncthreads();

    // outputs: boxes_with_scores [32][100][5], then classes [32][100]
    #pragma unroll
    for (int t = 0; t < 2; ++t) {
        int r = lane + (t << 6);
        if (r < MAXDET) {
            float* o = out + ((size_t)b * MAXDET + r) * 5;
            float* oc = out + (size_t)NB * MAXDET * 5 + (size_t)b * MAXDET + r;
            if (r < nk) {
                int i2 = s_keep[r];
                u64 key = skey[i2];
                int idx = (NANCHOR - 1) - (int)(key & 16383ULL);
                float score = __uint_as_float((u32)(key >> 14));
                float4 bx = ws_boxes[(size_t)b * NANCHOR + idx];
                int c = ws_cls[(size_t)b * NANCHOR + idx];
                o[0] = bx.x; o[1] = bx.y; o[2] = bx.z; o[3] = bx.w; o[4] = score;
                *oc = (float)c;
            } else {
                o[0] = 0.0f; o[1] = 0.0f; o[2] = 0.0f; o[3] = 0.0f; o[4] = 0.0f;
                *oc = -1.0f;
            }
        }
    }
}

extern "C" void kernel_launch(void* const* d_in, const int* in_sizes, int n_in,
                              void* d_out, int out_size, void* d_ws, size_t ws_size,
                              hipStream_t stream) {
    const float* cls0 = (const float*)d_in[0];
    const float* box0 = (const float*)d_in[1];
    const float* cls1 = (const float*)d_in[2];
    const float* box1 = (const float*)d_in[3];
    const float* cls2 = (const float*)d_in[4];
    const float* box2 = (const float*)d_in[5];

    float* ws = (float*)d_ws;
    float* ws_scores = ws;                                   // 268800 floats (reused for sorted data)
    float4* ws_boxes = (float4*)(ws + NB * NANCHOR);         // 268800 float4
    int* ws_cls = (int*)(ws + (size_t)NB * NANCHOR * 5);     // 268800 ints
    u64* ws_mask = (u64*)(ws + (size_t)NB * NANCHOR * 6);    // u64[32][1024][16] = 4 MB

    int total = NB * NANCHOR;
    decode_kernel<<<(total + 255) / 256, 256, 0, stream>>>(
        cls0, box0, cls1, box1, cls2, box2, ws_scores, ws_boxes, ws_cls);

    select_kernel<<<NB, 1024, 0, stream>>>(ws, ws_boxes, ws_cls);

    iou_mask_kernel<<<NB * 64, 256, 0, stream>>>(ws, ws_mask);

    nms_scan_kernel<<<NB, 64, 0, stream>>>(ws, ws_mask, ws_boxes, ws_cls, (float*)d_out);
}